// Round 11
// baseline (815.933 us; speedup 1.0000x reference)
//
#include <hip/hip_runtime.h>
#include <hip/hip_bf16.h>
#include <math.h>

// Problem constants
#define BB 2
#define HH 56
#define WW 56
#define LL (HH*WW)          // 3136
#define CM 96               // D_MODEL
#define DI 192              // D_INNER
#define NS 16               // D_STATE
#define NPIX (BB*LL)        // 6272
#define PROJ2 (2*DI)        // 384
#define SSMW (2*NS+1)       // 33
#define SSMW4 (4*SSMW)      // 132

// chunked scan: 3136 = NC * LC
#define NC 196
#define LC 16
#define RPAD 36             // LDS row: B[16]@0, C[16]@16, dt_raw@32
#define NBLK 1568           // persistent grid: all co-resident (see launch_bounds note)
#define GPB2 12             // scan-B groups (192 thr = 12 x 16)
#define CPG2 17             // chunks per group (12*17 = 204 >= 196)

typedef unsigned int uint32;

__device__ __forceinline__ float sigmoidf_(float v) { return 1.f / (1.f + __expf(-v)); }

__device__ __forceinline__ int dir_map(int k, int l) {
    if (k == 0) return l;
    if (k == 1) return LL - 1 - l;
    int l2 = (k == 2) ? l : (LL - 1 - l);
    return (l2 % HH) * WW + (l2 / HH);
}

__device__ __forceinline__ bool checkA(const float* A_log, int d) {
    bool ok = true;
    #pragma unroll
    for (int n = 0; n < NS; ++n) {
        float a = __expf(A_log[d*NS + n]);
        ok = ok && (fabsf(a - (float)(n+1)) < 1e-3f);
    }
    return ok;
}

// Grid barrier: arrivals spread over 64 cachelines (atomicAdd), polling via
// relaxed agent-scope atomic LOADS (no RMW serialization). Timeout guard turns
// a logic bug into wrong-results instead of a hang.
__device__ __forceinline__ void gridbar(uint32* ctr, int ph) {
    __syncthreads();                       // drains this block's stores (vmcnt0) to L2
    if (threadIdx.x == 0) {
        __threadfence();                   // release: L2 writeback device-visible
        atomicAdd(ctr + ph*1024 + (blockIdx.x & 63)*16, 1u);
    }
    if (threadIdx.x < 64) {
        int guard = 0;
        for (;;) {
            uint32 s = __hip_atomic_load(ctr + ph*1024 + threadIdx.x*16,
                                         __ATOMIC_RELAXED, __HIP_MEMORY_SCOPE_AGENT);
            #pragma unroll
            for (int o = 32; o; o >>= 1) s += __shfl_xor(s, o, 64);
            if (s >= NBLK || ++guard > (1<<18)) break;
            __builtin_amdgcn_s_sleep(1);
        }
        __threadfence();                   // acquire: invalidate stale L1/L2
    }
    __syncthreads();
}

__global__ __launch_bounds__(DI, 6) void k_mega(
    const float* __restrict__ x, const float* __restrict__ lng, const float* __restrict__ lnb,
    const float* __restrict__ W, const float* __restrict__ cw, const float* __restrict__ cb,
    const float* __restrict__ W2, const float* __restrict__ dt_w, const float* __restrict__ dt_b,
    const float* __restrict__ A_log, const float* __restrict__ Ds, const float* __restrict__ Wout,
    float* xproj, float* siluz, float* xc, float* ssm, float* ybuf,
    float* Hbuf, float* Sbuf, float* sdbuf, float* rpbuf,
    uint32* ctr, float* out)
{
    __shared__ float lds[3456];            // 13.9 KB union across phases
    int bid = blockIdx.x, t = threadIdx.x;

    // ---------- Phase 1: LayerNorm + in_proj (96->384), 8 px/tile, 784 tiles
    if (bid < NPIX/8) {
        int pix0 = bid * 8;
        ((float4*)lds)[t] = ((const float4*)(x + (size_t)pix0*CM))[t];   // 768 floats
        __syncthreads();
        if (t < 128) {
            int p = t >> 4, ln = t & 15;
            float v[6]; float s = 0.f;
            #pragma unroll
            for (int i = 0; i < 6; ++i) { v[i] = lds[p*96 + ln + 16*i]; s += v[i]; }
            #pragma unroll
            for (int o = 8; o; o >>= 1) s += __shfl_xor(s, o, 16);
            float mu = s * (1.f/96.f), q = 0.f;
            #pragma unroll
            for (int i = 0; i < 6; ++i) { float dv = v[i]-mu; q += dv*dv; }
            #pragma unroll
            for (int o = 8; o; o >>= 1) q += __shfl_xor(q, o, 16);
            float rstd = rsqrtf(q*(1.f/96.f) + 1e-5f);
            #pragma unroll
            for (int i = 0; i < 6; ++i)
                lds[p*96 + ln + 16*i] = (v[i]-mu)*rstd*lng[ln+16*i] + lnb[ln+16*i];
        }
        __syncthreads();
        float a0[8], a1[8];
        #pragma unroll
        for (int p = 0; p < 8; ++p) { a0[p] = 0.f; a1[p] = 0.f; }
        const float4* xsv = (const float4*)lds;
        for (int c4 = 0; c4 < 24; ++c4) {
            float w00 = W[(size_t)(4*c4+0)*PROJ2 + t],    w01 = W[(size_t)(4*c4+1)*PROJ2 + t];
            float w02 = W[(size_t)(4*c4+2)*PROJ2 + t],    w03 = W[(size_t)(4*c4+3)*PROJ2 + t];
            float w10 = W[(size_t)(4*c4+0)*PROJ2 + t+DI], w11 = W[(size_t)(4*c4+1)*PROJ2 + t+DI];
            float w12 = W[(size_t)(4*c4+2)*PROJ2 + t+DI], w13 = W[(size_t)(4*c4+3)*PROJ2 + t+DI];
            #pragma unroll
            for (int p = 0; p < 8; ++p) {
                float4 xv = xsv[p*24 + c4];
                a0[p] = fmaf(xv.x, w00, a0[p]); a0[p] = fmaf(xv.y, w01, a0[p]);
                a0[p] = fmaf(xv.z, w02, a0[p]); a0[p] = fmaf(xv.w, w03, a0[p]);
                a1[p] = fmaf(xv.x, w10, a1[p]); a1[p] = fmaf(xv.y, w11, a1[p]);
                a1[p] = fmaf(xv.z, w12, a1[p]); a1[p] = fmaf(xv.w, w13, a1[p]);
            }
        }
        #pragma unroll
        for (int p = 0; p < 8; ++p) {
            xproj[(size_t)(pix0+p)*DI + t] = a0[p];          // outputs 0..191
            float v = a1[p];                                  // outputs 192..383 -> z[t]
            siluz[(size_t)(pix0+p)*DI + t] = v * sigmoidf_(v);
        }
    }
    gridbar(ctr, 0);

    // ---------- Phase 2: depthwise 3x3 conv + SiLU, 4-wide tiles, 1568 tiles (1:1)
    {
        int wq = bid % 14; int rest = bid / 14;
        int h = rest % HH; int b = rest / HH;
        int w0 = wq * 4;
        for (int i4 = t; i4 < 3*6*48; i4 += DI) {
            int c4 = i4 % 48; int col = (i4/48) % 6; int row = i4 / 288;
            int hh = h - 1 + row, ww = w0 - 1 + col;
            float4 v = {0.f,0.f,0.f,0.f};
            if (hh >= 0 && hh < HH && ww >= 0 && ww < WW)
                v = ((const float4*)(xproj + ((size_t)(b*LL + hh*WW + ww))*DI))[c4];
            ((float4*)lds)[(row*6 + col)*48 + c4] = v;
        }
        __syncthreads();
        float wgt[9];
        #pragma unroll
        for (int q = 0; q < 9; ++q) wgt[q] = cw[t*9 + q];
        float bias = cb[t];
        #pragma unroll
        for (int dw = 0; dw < 4; ++dw) {
            float acc = bias;
            #pragma unroll
            for (int r = 0; r < 3; ++r)
                #pragma unroll
                for (int cc = 0; cc < 3; ++cc)
                    acc = fmaf(lds[(r*6 + dw + cc)*DI + t], wgt[r*3+cc], acc);
            xc[((size_t)(b*LL + h*WW + w0 + dw))*DI + t] = acc * sigmoidf_(acc);
        }
    }
    gridbar(ctr, 1);

    // ---------- Phase 3: ssm projection xc(192) @ W2(192,132), 8 px/tile, 784 tiles
    if (bid < NPIX/8) {
        int pix0 = bid * 8;
        ((float4*)lds)[t]      = ((const float4*)(xc + (size_t)pix0*DI))[t];
        ((float4*)lds)[t + DI] = ((const float4*)(xc + (size_t)pix0*DI))[t + DI];
        __syncthreads();
        if (t < SSMW4) {
            float acc[8];
            #pragma unroll
            for (int p = 0; p < 8; ++p) acc[p] = 0.f;
            const float4* xv4 = (const float4*)lds;
            for (int c4 = 0; c4 < 48; ++c4) {
                float w0_ = W2[(size_t)(4*c4+0)*SSMW4 + t], w1_ = W2[(size_t)(4*c4+1)*SSMW4 + t];
                float w2_ = W2[(size_t)(4*c4+2)*SSMW4 + t], w3_ = W2[(size_t)(4*c4+3)*SSMW4 + t];
                #pragma unroll
                for (int p = 0; p < 8; ++p) {
                    float4 xv = xv4[p*48 + c4];
                    acc[p] = fmaf(xv.x, w0_, acc[p]); acc[p] = fmaf(xv.y, w1_, acc[p]);
                    acc[p] = fmaf(xv.z, w2_, acc[p]); acc[p] = fmaf(xv.w, w3_, acc[p]);
                }
            }
            #pragma unroll
            for (int p = 0; p < 8; ++p) ssm[(size_t)(pix0+p)*SSMW4 + t] = acc[p];
        }
    }
    gridbar(ctr, 2);

    // ---------- Scan setup (phases 4 & 6 share chunk mapping; 1568 chunks 1:1)
    int c_ = bid % NC, kb = bid / NC;
    int sb = kb & 1, sk = kb >> 1;
    int l0 = c_ * LC;
    int j0 = dir_map(sk, l0);
    int dj = (sk==0) ? 1 : (sk==1) ? -1 : (sk==2) ? WW : -WW;
    const float* xcb = xc + (size_t)sb*LL*DI;
    size_t tc = (size_t)kb*DI*NC + (size_t)t*NC + c_;   // scan-major state index
    bool fast = checkA(A_log, t);
    float dtw = dt_w[sk*DI + t], dtb = dt_b[sk*DI + t], Dk = Ds[sk*DI + t];

    float r_[LC], dx_[LC], xdk_[LC];        // cached across phases 4->6 (FAST path)

    // ---------- Phase 4: local chunk scan (h=0); rows stay in LDS[0..576)
    {
        const float* ssmb = ssm + (size_t)sb*LL*SSMW4 + SSMW*sk;
        for (int i = t; i < LC*SSMW; i += DI) {
            int r = i / SSMW, w = i % SSMW;
            lds[r*RPAD + ((w == 0) ? 32 : (w - 1))] = ssmb[(size_t)(l0 + r)*SSMW4 + w];
        }
        __syncthreads();
        float h[NS];
        #pragma unroll
        for (int n = 0; n < NS; ++n) h[n] = 0.f;
        float sumdt = 0.f, rprod = 1.f;
        if (fast) {
            int j = j0;
            #pragma unroll
            for (int li = 0; li < LC; ++li) {
                float pre = fmaf(lds[li*RPAD + 32], dtw, dtb);
                float t1 = __expf(-fabsf(pre)); float opt = 1.f + t1;
                float dt = fmaxf(pre, 0.f) + __logf(opt);
                float r = ((pre >= 0.f) ? t1 : 1.f) * __builtin_amdgcn_rcpf(opt);
                sumdt += dt; rprod *= r;
                float xt = xcb[(size_t)j*DI + t];
                float dx = dt * xt;
                r_[li] = r; dx_[li] = dx; xdk_[li] = xt * Dk;
                float pw[NS];
                pw[0]=r;           pw[1]=r*r;         pw[2]=pw[1]*r;     pw[3]=pw[1]*pw[1];
                pw[4]=pw[3]*r;     pw[5]=pw[3]*pw[1]; pw[6]=pw[3]*pw[2]; pw[7]=pw[3]*pw[3];
                pw[8]=pw[7]*r;     pw[9]=pw[7]*pw[1]; pw[10]=pw[7]*pw[2];pw[11]=pw[7]*pw[3];
                pw[12]=pw[7]*pw[4];pw[13]=pw[7]*pw[5];pw[14]=pw[7]*pw[6];pw[15]=pw[7]*pw[7];
                const float4* Bv = (const float4*)(lds + li*RPAD);
                #pragma unroll
                for (int q = 0; q < 4; ++q) {
                    float4 bq = Bv[q];
                    h[4*q+0] = fmaf(pw[4*q+0], h[4*q+0], dx * bq.x);
                    h[4*q+1] = fmaf(pw[4*q+1], h[4*q+1], dx * bq.y);
                    h[4*q+2] = fmaf(pw[4*q+2], h[4*q+2], dx * bq.z);
                    h[4*q+3] = fmaf(pw[4*q+3], h[4*q+3], dx * bq.w);
                }
                j += dj;
                if (j >= LL) j -= LL-1; else if (j < 0) j += LL-1;
            }
        } else {
            float negA[NS];
            #pragma unroll
            for (int n = 0; n < NS; ++n) negA[n] = -__expf(A_log[t*NS + n]);
            int j = j0;
            for (int li = 0; li < LC; ++li) {
                float pre = fmaf(lds[li*RPAD + 32], dtw, dtb);
                float t1 = __expf(-fabsf(pre)); float opt = 1.f + t1;
                float dt = fmaxf(pre, 0.f) + __logf(opt);
                sumdt += dt;
                float xt = xcb[(size_t)j*DI + t];
                float dx = dt * xt;
                const float4* Bv = (const float4*)(lds + li*RPAD);
                #pragma unroll
                for (int q = 0; q < 4; ++q) {
                    float4 bq = Bv[q];
                    h[4*q+0] = fmaf(__expf(dt*negA[4*q+0]), h[4*q+0], dx * bq.x);
                    h[4*q+1] = fmaf(__expf(dt*negA[4*q+1]), h[4*q+1], dx * bq.y);
                    h[4*q+2] = fmaf(__expf(dt*negA[4*q+2]), h[4*q+2], dx * bq.z);
                    h[4*q+3] = fmaf(__expf(dt*negA[4*q+3]), h[4*q+3], dx * bq.w);
                }
                j += dj;
                if (j >= LL) j -= LL-1; else if (j < 0) j += LL-1;
            }
        }
        float4* Hp = (float4*)(Hbuf + tc*NS);
        #pragma unroll
        for (int q = 0; q < 4; ++q) Hp[q] = make_float4(h[4*q+0], h[4*q+1], h[4*q+2], h[4*q+3]);
        sdbuf[tc] = sumdt;
        rpbuf[tc] = rprod;
    }
    gridbar(ctr, 3);

    // ---------- Phase 5: exclusive prefix over chunks per (kb,d); 1536 tasks
    if (bid < 4*BB*DI) {
        int wid = bid, d2 = wid % DI;
        bool fast2 = checkA(A_log, d2);
        int n2 = t & 15, g2 = t >> 4;
        float negA2 = -__expf(A_log[d2*NS + n2]);
        int e = n2 + 1;
        size_t base = (size_t)wid * NC;
        int c0 = g2 * CPG2;
        float (*Ag)[16] = (float(*)[16])(lds + 576);
        float (*Hg)[16] = (float(*)[16])(lds + 576 + GPB2*16);
        float (*Sg)[16] = (float(*)[16])(lds + 576 + 2*GPB2*16);
        float Pv[CPG2], Hl[CPG2];
        float A = 1.f, H = 0.f;
        #pragma unroll
        for (int i = 0; i < CPG2; ++i) {
            bool ok = (c0 + i) < NC;
            size_t cc = base + (ok ? c0 + i : 0);
            float P;
            if (fast2) {
                float r = rpbuf[cc];
                float p2 = r*r, p4 = p2*p2, p8 = p4*p4;
                P = ((e&1)?r:1.f)*((e&2)?p2:1.f)*((e&4)?p4:1.f)*((e&8)?p8:1.f)*((e&16)?p8*p8:1.f);
            } else {
                P = __expf(negA2 * sdbuf[cc]);
            }
            float hl = Hbuf[cc*NS + n2];
            if (!ok) { P = 1.f; hl = 0.f; }
            Pv[i] = P; Hl[i] = hl;
            H = fmaf(P, H, hl); A *= P;
        }
        Ag[g2][n2] = A; Hg[g2][n2] = H;
        __syncthreads();
        if (t < 16) {
            float s = 0.f;
            #pragma unroll
            for (int gg = 0; gg < GPB2; ++gg) { Sg[gg][t] = s; s = fmaf(Ag[gg][t], s, Hg[gg][t]); }
        }
        __syncthreads();
        float s = Sg[g2][n2];
        #pragma unroll
        for (int i = 0; i < CPG2; ++i) {
            if ((c0 + i) < NC) Sbuf[(base + c0 + i)*NS + n2] = s;
            s = fmaf(Pv[i], s, Hl[i]);
        }
    }
    gridbar(ctr, 4);

    // ---------- Phase 6: re-scan from incoming state; rows LDS + r_/dx_/xdk_ still live
    {
        float h[NS];
        const float4* Sp = (const float4*)(Sbuf + tc*NS);
        #pragma unroll
        for (int q = 0; q < 4; ++q) {
            float4 v = Sp[q];
            h[4*q+0] = v.x; h[4*q+1] = v.y; h[4*q+2] = v.z; h[4*q+3] = v.w;
        }
        float* yb = ybuf + ((size_t)sk*BB + sb)*LL*DI;
        if (fast) {
            int j = j0;
            #pragma unroll
            for (int li = 0; li < LC; ++li) {
                float r = r_[li], dx = dx_[li];
                float pw[NS];
                pw[0]=r;           pw[1]=r*r;         pw[2]=pw[1]*r;     pw[3]=pw[1]*pw[1];
                pw[4]=pw[3]*r;     pw[5]=pw[3]*pw[1]; pw[6]=pw[3]*pw[2]; pw[7]=pw[3]*pw[3];
                pw[8]=pw[7]*r;     pw[9]=pw[7]*pw[1]; pw[10]=pw[7]*pw[2];pw[11]=pw[7]*pw[3];
                pw[12]=pw[7]*pw[4];pw[13]=pw[7]*pw[5];pw[14]=pw[7]*pw[6];pw[15]=pw[7]*pw[7];
                const float4* Bv = (const float4*)(lds + li*RPAD);
                const float4* Cv = Bv + 4;
                float y0 = 0.f, y1 = 0.f;
                #pragma unroll
                for (int q = 0; q < 4; ++q) {
                    float4 bq = Bv[q]; float4 cq = Cv[q];
                    h[4*q+0] = fmaf(pw[4*q+0], h[4*q+0], dx * bq.x);
                    h[4*q+1] = fmaf(pw[4*q+1], h[4*q+1], dx * bq.y);
                    h[4*q+2] = fmaf(pw[4*q+2], h[4*q+2], dx * bq.z);
                    h[4*q+3] = fmaf(pw[4*q+3], h[4*q+3], dx * bq.w);
                    y0 = fmaf(h[4*q+0], cq.x, y0); y1 = fmaf(h[4*q+1], cq.y, y1);
                    y0 = fmaf(h[4*q+2], cq.z, y0); y1 = fmaf(h[4*q+3], cq.w, y1);
                }
                yb[(size_t)j*DI + t] = y0 + y1 + xdk_[li];
                j += dj;
                if (j >= LL) j -= LL-1; else if (j < 0) j += LL-1;
            }
        } else {
            float negA[NS];
            #pragma unroll
            for (int n = 0; n < NS; ++n) negA[n] = -__expf(A_log[t*NS + n]);
            int j = j0;
            for (int li = 0; li < LC; ++li) {
                float pre = fmaf(lds[li*RPAD + 32], dtw, dtb);
                float t1 = __expf(-fabsf(pre)); float opt = 1.f + t1;
                float dt = fmaxf(pre, 0.f) + __logf(opt);
                float xt = xcb[(size_t)j*DI + t];
                float dx = dt * xt;
                const float4* Bv = (const float4*)(lds + li*RPAD);
                const float4* Cv = Bv + 4;
                float y0 = 0.f, y1 = 0.f;
                #pragma unroll
                for (int q = 0; q < 4; ++q) {
                    float4 bq = Bv[q]; float4 cq = Cv[q];
                    h[4*q+0] = fmaf(__expf(dt*negA[4*q+0]), h[4*q+0], dx * bq.x);
                    h[4*q+1] = fmaf(__expf(dt*negA[4*q+1]), h[4*q+1], dx * bq.y);
                    h[4*q+2] = fmaf(__expf(dt*negA[4*q+2]), h[4*q+2], dx * bq.z);
                    h[4*q+3] = fmaf(__expf(dt*negA[4*q+3]), h[4*q+3], dx * bq.w);
                    y0 = fmaf(h[4*q+0], cq.x, y0); y1 = fmaf(h[4*q+1], cq.y, y1);
                    y0 = fmaf(h[4*q+2], cq.z, y0); y1 = fmaf(h[4*q+3], cq.w, y1);
                }
                yb[(size_t)j*DI + t] = fmaf(xt, Dk, y0 + y1);
                j += dj;
                if (j >= LL) j -= LL-1; else if (j < 0) j += LL-1;
            }
        }
    }
    gridbar(ctr, 5);

    // ---------- Phase 7: sum 4 dirs, gate silu(z), out_proj + residual; 392 tiles of 16 px
    if (bid < NPIX/16) {
        int pix0 = bid * 16;
        const size_t stride4 = (size_t)BB*LL*(DI/4);
        for (int i4 = t; i4 < 16*(DI/4); i4 += DI) {
            size_t g4 = (size_t)pix0*(DI/4) + i4;
            float4 a  = ((const float4*)ybuf)[g4];
            float4 b1 = ((const float4*)ybuf)[g4 + stride4];
            float4 c1 = ((const float4*)ybuf)[g4 + 2*stride4];
            float4 d1 = ((const float4*)ybuf)[g4 + 3*stride4];
            float4 z  = ((const float4*)siluz)[g4];
            float4 rr;
            rr.x = (a.x+b1.x+c1.x+d1.x) * z.x;
            rr.y = (a.y+b1.y+c1.y+d1.y) * z.y;
            rr.z = (a.z+b1.z+c1.z+d1.z) * z.z;
            rr.w = (a.w+b1.w+c1.w+d1.w) * z.w;
            ((float4*)lds)[i4] = rr;
        }
        __syncthreads();
        int ph = t / CM, oc = t - ph*CM;
        float acc[8];
        #pragma unroll
        for (int p = 0; p < 8; ++p) acc[p] = x[(size_t)(pix0 + ph*8 + p)*CM + oc];
        const float4* pv = (const float4*)lds;
        for (int c4 = 0; c4 < 48; ++c4) {
            float w0_ = Wout[(size_t)(4*c4+0)*CM + oc], w1_ = Wout[(size_t)(4*c4+1)*CM + oc];
            float w2_ = Wout[(size_t)(4*c4+2)*CM + oc], w3_ = Wout[(size_t)(4*c4+3)*CM + oc];
            #pragma unroll
            for (int p = 0; p < 8; ++p) {
                float4 xv = pv[(ph*8 + p)*48 + c4];
                acc[p] = fmaf(xv.x, w0_, acc[p]); acc[p] = fmaf(xv.y, w1_, acc[p]);
                acc[p] = fmaf(xv.z, w2_, acc[p]); acc[p] = fmaf(xv.w, w3_, acc[p]);
            }
        }
        #pragma unroll
        for (int p = 0; p < 8; ++p) out[(size_t)(pix0 + ph*8 + p)*CM + oc] = acc[p];
    }
}

extern "C" void kernel_launch(void* const* d_in, const int* in_sizes, int n_in,
                              void* d_out, int out_size, void* d_ws, size_t ws_size,
                              hipStream_t stream) {
    const float* x        = (const float*)d_in[0];
    const float* ln_g     = (const float*)d_in[1];
    const float* ln_b     = (const float*)d_in[2];
    const float* in_projw = (const float*)d_in[3];
    const float* conv_w   = (const float*)d_in[4];
    const float* conv_b   = (const float*)d_in[5];
    const float* x_projw  = (const float*)d_in[6];
    const float* dt_w     = (const float*)d_in[7];
    const float* dt_b     = (const float*)d_in[8];
    const float* A_log    = (const float*)d_in[9];
    const float* Ds       = (const float*)d_in[10];
    const float* out_projw= (const float*)d_in[11];
    float* out = (float*)d_out;

    // workspace layout (floats) — ~76 MB + 24 KB barrier counters
    float* ws = (float*)d_ws;
    size_t n192 = (size_t)NPIX * DI;          // 1,204,224
    size_t n132 = (size_t)NPIX * SSMW4;       // 827,904
    size_t nchk = (size_t)4*BB*NC*DI;         // 301,056
    float* xproj = ws;
    float* siluz = xproj + n192;
    float* xc    = siluz + n192;
    float* ssm   = xc + n192;
    float* ybuf  = ssm + n132;                // 4 * n192
    float* Hbuf  = ybuf + 4*n192;             // nchk * NS
    float* Sbuf  = Hbuf + nchk*NS;            // nchk * NS
    float* sdbuf = xproj;                     // alias: xproj dead after conv phase (barrier-ordered)
    float* rpbuf = xproj + nchk;
    uint32* ctr  = (uint32*)(Sbuf + nchk*NS); // 6 * 1024 uints

    hipMemsetAsync(ctr, 0, 6*1024*sizeof(uint32), stream);
    k_mega<<<NBLK, DI, 0, stream>>>(
        x, ln_g, ln_b, in_projw, conv_w, conv_b, x_projw, dt_w, dt_b, A_log, Ds, out_projw,
        xproj, siluz, xc, ssm, ybuf, Hbuf, Sbuf, sdbuf, rpbuf, ctr, out);
}

// Round 12
// 199.855 us; speedup vs baseline: 4.0826x; 4.0826x over previous
//
#include <hip/hip_runtime.h>
#include <hip/hip_bf16.h>
#include <math.h>

// Problem constants (from reference)
#define BB 2
#define HH 56
#define WW 56
#define LL (HH*WW)          // 3136
#define CM 96               // D_MODEL
#define DI 192              // D_INNER
#define NS 16               // D_STATE
#define NPIX (BB*LL)        // 6272
#define PROJ2 (2*DI)        // 384
#define SSMW (2*NS+1)       // 33
#define SSMW4 (4*SSMW)      // 132

// chunked scan decomposition: 3136 = NC * LC
#define NC 196
#define LC 16
#define RPAD 36             // padded LDS row: B[16] @0, C[16] @16, dt_raw @32 (144B, 16B-aligned)
#define GPB 16              // scan2: groups per block
#define CPG 13              // scan2: chunks per group (15*13 + 1 = 196)

__device__ __forceinline__ float sigmoidf_(float v) { return 1.f / (1.f + __expf(-v)); }

__device__ __forceinline__ int dir_map(int k, int l) {
    if (k == 0) return l;
    if (k == 1) return LL - 1 - l;
    int l2 = (k == 2) ? l : (LL - 1 - l);
    return (l2 % HH) * WW + (l2 / HH);   // column-major <-> row-major remap
}

// ---------------- Kernel A: LayerNorm + in_proj (96 -> 384), 16 pixels/block
__global__ __launch_bounds__(384) void k_ln_inproj(
    const float* __restrict__ x, const float* __restrict__ g, const float* __restrict__ bta,
    const float* __restrict__ W, float* __restrict__ xproj, float* __restrict__ siluz)
{
    int pix0 = blockIdx.x * 16;
    int t = threadIdx.x;
    __shared__ float xs[16*96];        // 6 KB
    ((float4*)xs)[t] = ((const float4*)(x + (size_t)pix0*CM))[t];   // 384 float4 = 1536 floats
    __syncthreads();
    if (t < 256) {
        int p = t >> 4, ln = t & 15;     // 16 pixels x 16 lanes
        float v[6]; float s = 0.f;
        #pragma unroll
        for (int i = 0; i < 6; ++i) { v[i] = xs[p*96 + ln + 16*i]; s += v[i]; }
        #pragma unroll
        for (int o = 8; o; o >>= 1) s += __shfl_xor(s, o, 16);
        float mu = s * (1.f/96.f);
        float q = 0.f;
        #pragma unroll
        for (int i = 0; i < 6; ++i) { float dvi = v[i]-mu; q += dvi*dvi; }
        #pragma unroll
        for (int o = 8; o; o >>= 1) q += __shfl_xor(q, o, 16);
        float rstd = rsqrtf(q*(1.f/96.f) + 1e-5f);
        #pragma unroll
        for (int i = 0; i < 6; ++i)
            xs[p*96 + ln + 16*i] = (v[i]-mu)*rstd*g[ln+16*i] + bta[ln+16*i];
    }
    __syncthreads();
    float acc[16];
    #pragma unroll
    for (int p = 0; p < 16; ++p) acc[p] = 0.f;
    const float4* xsv = (const float4*)xs;
    for (int c4 = 0; c4 < CM/4; ++c4) {
        float w0 = W[(size_t)(4*c4+0)*PROJ2 + t];
        float w1 = W[(size_t)(4*c4+1)*PROJ2 + t];
        float w2 = W[(size_t)(4*c4+2)*PROJ2 + t];
        float w3 = W[(size_t)(4*c4+3)*PROJ2 + t];
        #pragma unroll
        for (int p = 0; p < 16; ++p) {
            float4 xv = xsv[p*24 + c4];
            acc[p] = fmaf(xv.x, w0, acc[p]);
            acc[p] = fmaf(xv.y, w1, acc[p]);
            acc[p] = fmaf(xv.z, w2, acc[p]);
            acc[p] = fmaf(xv.w, w3, acc[p]);
        }
    }
    if (t < DI) {
        #pragma unroll
        for (int p = 0; p < 16; ++p) xproj[(size_t)(pix0+p)*DI + t] = acc[p];
    } else {
        int o = t - DI;
        #pragma unroll
        for (int p = 0; p < 16; ++p) { float v = acc[p]; siluz[(size_t)(pix0+p)*DI + o] = v * sigmoidf_(v); }
    }
}

// ---------------- Kernel B: depthwise 3x3 conv + SiLU fused with ssm projection
__global__ __launch_bounds__(DI) void k_convx(
    const float* __restrict__ xproj, const float* __restrict__ cw, const float* __restrict__ cb,
    const float* __restrict__ W2, float* __restrict__ xc, float* __restrict__ ssm)
{
    int blk = blockIdx.x;                  // b*HH*7 + h*7 + wq
    int wq = blk % 7; int rest = blk / 7;
    int h = rest % HH; int b = rest / HH;
    int w0 = wq * 8;
    int t = threadIdx.x;                   // channel
    __shared__ float xs[3][10][DI];        // 23 KB halo tile
    __shared__ float xcs[8*DI];            // 6 KB conv outputs
    for (int i4 = t; i4 < 3*10*(DI/4); i4 += DI) {
        int c4 = i4 % (DI/4); int col = (i4/(DI/4)) % 10; int row = i4 / (10*(DI/4));
        int hh = h - 1 + row, ww = w0 - 1 + col;
        float4 v = {0.f,0.f,0.f,0.f};
        if (hh >= 0 && hh < HH && ww >= 0 && ww < WW)
            v = ((const float4*)(xproj + ((size_t)(b*LL + hh*WW + ww))*DI))[c4];
        ((float4*)&xs[row][col][0])[c4] = v;
    }
    __syncthreads();
    float wgt[9];
    #pragma unroll
    for (int q = 0; q < 9; ++q) wgt[q] = cw[t*9 + q];
    float bias = cb[t];
    int pixbase = b*LL + h*WW + w0;
    #pragma unroll
    for (int dw = 0; dw < 8; ++dw) {
        float acc = bias;
        #pragma unroll
        for (int r = 0; r < 3; ++r)
            #pragma unroll
            for (int cc = 0; cc < 3; ++cc)
                acc = fmaf(xs[r][dw+cc][t], wgt[r*3+cc], acc);
        float v = acc * sigmoidf_(acc);
        xc[((size_t)(pixbase + dw))*DI + t] = v;
        xcs[dw*DI + t] = v;
    }
    __syncthreads();
    if (t < SSMW4) {
        float acc[8] = {0.f,0.f,0.f,0.f,0.f,0.f,0.f,0.f};
        const float4* xsv = (const float4*)xcs;
        for (int c4 = 0; c4 < DI/4; ++c4) {
            float w0_ = W2[(size_t)(4*c4+0)*SSMW4 + t];
            float w1_ = W2[(size_t)(4*c4+1)*SSMW4 + t];
            float w2_ = W2[(size_t)(4*c4+2)*SSMW4 + t];
            float w3_ = W2[(size_t)(4*c4+3)*SSMW4 + t];
            #pragma unroll
            for (int p = 0; p < 8; ++p) {
                float4 xv = xsv[p*48 + c4];
                acc[p] = fmaf(xv.x, w0_, acc[p]);
                acc[p] = fmaf(xv.y, w1_, acc[p]);
                acc[p] = fmaf(xv.z, w2_, acc[p]);
                acc[p] = fmaf(xv.w, w3_, acc[p]);
            }
        }
        #pragma unroll
        for (int p = 0; p < 8; ++p) ssm[(size_t)(pixbase+p)*SSMW4 + t] = acc[p];
    }
}

// stage LC rows of the 33-wide ssm slice into padded LDS layout:
// lds[r*RPAD + 0..15] = B, [16..31] = C, [32] = dt_raw
__device__ __forceinline__ void stage_rows(float* rows, const float* ssmb, int l0, int d) {
    for (int i = d; i < LC*SSMW; i += DI) {
        int r = i / SSMW, w = i % SSMW;
        int dst = (w == 0) ? 32 : (w - 1);
        rows[r*RPAD + dst] = ssmb[(size_t)(l0 + r)*SSMW4 + w];
    }
}

// per-chunk scan body.  FAST: exploits A[d][n] = n+1 (verified at runtime) so
// dA_n = r^(n+1) with r = sigmoid(-pre) — no per-n transcendentals.
// LC loop fully unrolled: lets the compiler hoist the 16 independent xcb loads
// (j chain is cheap ALU) ahead of the dependent fma chains.
template<bool FAST, bool WRITEY>
__device__ __forceinline__ void scan_chunk(
    const float* rows, const float* xcb, float* yb,
    int j0, int dj, float dtw, float dtb, float Dk,
    const float* A_log, int d, float* h, float* sumdt_out, float* rprod_out)
{
    float negA[NS];
    if (!FAST) {
        #pragma unroll
        for (int n = 0; n < NS; ++n) negA[n] = -__expf(A_log[d*NS + n]);
    }
    float sumdt = 0.f;
    float rprod = 1.f;
    int j = j0;
    #pragma unroll
    for (int li = 0; li < LC; ++li) {
        const float4* Bv = (const float4*)(rows + li*RPAD);
        const float4* Cv = Bv + 4;
        float pre = fmaf(rows[li*RPAD + 32], dtw, dtb);
        float t1 = __expf(-fabsf(pre));
        float opt = 1.f + t1;
        float dt = fmaxf(pre, 0.f) + __logf(opt);     // softplus, stable
        sumdt += dt;
        float xt = xcb[(size_t)j*DI + d];
        float dx = dt * xt;
        float pw[NS];
        if (FAST) {
            // r = exp(-dt) = sigmoid(-pre);  pw[n] = r^(n+1), depth-4 mul tree
            float r = ((pre >= 0.f) ? t1 : 1.f) * __builtin_amdgcn_rcpf(opt);
            rprod *= r;
            pw[0]=r;          pw[1]=r*r;        pw[2]=pw[1]*r;     pw[3]=pw[1]*pw[1];
            pw[4]=pw[3]*r;    pw[5]=pw[3]*pw[1];pw[6]=pw[3]*pw[2]; pw[7]=pw[3]*pw[3];
            pw[8]=pw[7]*r;    pw[9]=pw[7]*pw[1];pw[10]=pw[7]*pw[2];pw[11]=pw[7]*pw[3];
            pw[12]=pw[7]*pw[4];pw[13]=pw[7]*pw[5];pw[14]=pw[7]*pw[6];pw[15]=pw[7]*pw[7];
        } else {
            #pragma unroll
            for (int n = 0; n < NS; ++n) pw[n] = __expf(dt * negA[n]);
        }
        float y0 = 0.f, y1 = 0.f;
        #pragma unroll
        for (int q = 0; q < 4; ++q) {
            float4 bq = Bv[q];
            h[4*q+0] = fmaf(pw[4*q+0], h[4*q+0], dx * bq.x);
            h[4*q+1] = fmaf(pw[4*q+1], h[4*q+1], dx * bq.y);
            h[4*q+2] = fmaf(pw[4*q+2], h[4*q+2], dx * bq.z);
            h[4*q+3] = fmaf(pw[4*q+3], h[4*q+3], dx * bq.w);
            if (WRITEY) {
                float4 cq = Cv[q];
                y0 = fmaf(h[4*q+0], cq.x, y0);
                y1 = fmaf(h[4*q+1], cq.y, y1);
                y0 = fmaf(h[4*q+2], cq.z, y0);
                y1 = fmaf(h[4*q+3], cq.w, y1);
            }
        }
        if (WRITEY) yb[(size_t)j*DI + d] = fmaf(xt, Dk, y0 + y1);
        // incremental direction map: +1 / -1 / +56 wrap / -56 wrap
        j += dj;
        if (j >= LL) j -= LL-1; else if (j < 0) j += LL-1;
    }
    *sumdt_out = sumdt;
    *rprod_out = rprod;
}

__device__ __forceinline__ bool checkA(const float* A_log, int d) {
    bool ok = true;
    #pragma unroll
    for (int n = 0; n < NS; ++n) {
        float a = __expf(A_log[d*NS + n]);
        ok = ok && (fabsf(a - (float)(n+1)) < 1e-3f);
    }
    return ok;
}

// ---------------- Scan phase 1: per-chunk local scan (h_in = 0)
// Outputs in scan-major layout: Hbuf[((kb*DI+d)*NC + c)*NS + n], sdbuf/rpbuf[(kb*DI+d)*NC + c]
__global__ __launch_bounds__(DI) void k_scan1(
    const float* __restrict__ ssm, const float* __restrict__ xc,
    const float* __restrict__ A_log, const float* __restrict__ dt_w,
    const float* __restrict__ dt_b,
    float* __restrict__ Hbuf, float* __restrict__ sdbuf, float* __restrict__ rpbuf)
{
    int idx = blockIdx.x;          // ((k*2+b)*NC + c)
    int c  = idx % NC;
    int kb = idx / NC;
    int b = kb & 1;
    int k = kb >> 1;
    int d = threadIdx.x;

    __shared__ float rows[LC*RPAD];
    const float* ssmb = ssm + (size_t)b*LL*SSMW4 + SSMW*k;
    int l0 = c * LC;
    stage_rows(rows, ssmb, l0, d);
    __syncthreads();

    float dtw = dt_w[k*DI + d];
    float dtb = dt_b[k*DI + d];
    float h[NS];
    #pragma unroll
    for (int n = 0; n < NS; ++n) h[n] = 0.f;
    float sumdt, rprod;
    int j0 = dir_map(k, l0);
    int dj = (k==0) ? 1 : (k==1) ? -1 : (k==2) ? WW : -WW;
    const float* xcb = xc + (size_t)b*LL*DI;

    if (checkA(A_log, d))
        scan_chunk<true , false>(rows, xcb, nullptr, j0, dj, dtw, dtb, 0.f, A_log, d, h, &sumdt, &rprod);
    else
        scan_chunk<false, false>(rows, xcb, nullptr, j0, dj, dtw, dtb, 0.f, A_log, d, h, &sumdt, &rprod);

    size_t tc = (size_t)kb*DI*NC + (size_t)d*NC + c;      // transposed chunk index
    float4* Hp = (float4*)(Hbuf + tc*NS);
    #pragma unroll
    for (int q = 0; q < 4; ++q) Hp[q] = make_float4(h[4*q+0], h[4*q+1], h[4*q+2], h[4*q+3]);
    sdbuf[tc] = sumdt;
    rpbuf[tc] = rprod;
}

// ---------------- Scan phase 2: block-parallel exclusive prefix per (kb,d).
__global__ __launch_bounds__(256) void k_scan2(
    const float* __restrict__ Hbuf, float* __restrict__ Sbuf,
    const float* __restrict__ sdbuf, const float* __restrict__ rpbuf,
    const float* __restrict__ A_log)
{
    int wid = blockIdx.x;            // kb*DI + d
    int d  = wid % DI;
    int t = threadIdx.x;
    int n = t & 15, g = t >> 4;
    bool fast = checkA(A_log, d);
    float negA = -__expf(A_log[d*NS + n]);
    int e = n + 1;
    size_t base = (size_t)wid * NC;
    int c0 = g * CPG;

    __shared__ float Ag[GPB][16], Hg[GPB][16], Sg[GPB][16];

    float Pv[CPG], Hl[CPG];
    float A = 1.f, H = 0.f;
    #pragma unroll
    for (int i = 0; i < CPG; ++i) {
        bool ok = (c0 + i) < NC;
        size_t c = base + (ok ? c0 + i : 0);
        float P;
        if (fast) {
            float r = rpbuf[c];
            float p2=r*r, p4=p2*p2, p8=p4*p4;
            P = ((e&1)?r:1.f)*((e&2)?p2:1.f)*((e&4)?p4:1.f)*((e&8)?p8:1.f)*((e&16)?p8*p8:1.f);
        } else {
            P = __expf(negA * sdbuf[c]);
        }
        float hl = Hbuf[c*NS + n];
        if (!ok) { P = 1.f; hl = 0.f; }   // identity map for tail lanes
        Pv[i] = P; Hl[i] = hl;
        H = fmaf(P, H, hl);
        A *= P;
    }
    Ag[g][n] = A; Hg[g][n] = H;
    __syncthreads();
    if (t < 16) {
        float s = 0.f;
        #pragma unroll
        for (int gg = 0; gg < GPB; ++gg) {
            Sg[gg][t] = s;
            s = fmaf(Ag[gg][t], s, Hg[gg][t]);
        }
    }
    __syncthreads();
    float s = Sg[g][n];
    #pragma unroll
    for (int i = 0; i < CPG; ++i) {
        if ((c0 + i) < NC) Sbuf[(base + c0 + i)*NS + n] = s;
        s = fmaf(Pv[i], s, Hl[i]);
    }
}

// ---------------- Scan phase 3: re-scan chunk from incoming state, write y per direction
__global__ __launch_bounds__(DI) void k_scan3(
    const float* __restrict__ ssm, const float* __restrict__ xc,
    const float* __restrict__ A_log, const float* __restrict__ dt_w,
    const float* __restrict__ dt_b, const float* __restrict__ Ds,
    const float* __restrict__ Sbuf, float* __restrict__ ybuf)
{
    int idx = blockIdx.x;
    int c  = idx % NC;
    int kb = idx / NC;
    int b = kb & 1;
    int k = kb >> 1;
    int d = threadIdx.x;

    __shared__ float rows[LC*RPAD];
    const float* ssmb = ssm + (size_t)b*LL*SSMW4 + SSMW*k;
    int l0 = c * LC;
    stage_rows(rows, ssmb, l0, d);
    __syncthreads();

    float dtw = dt_w[k*DI + d];
    float dtb = dt_b[k*DI + d];
    float Dk  = Ds[k*DI + d];
    float h[NS];
    size_t tc = (size_t)kb*DI*NC + (size_t)d*NC + c;      // transposed chunk index
    const float4* Sp = (const float4*)(Sbuf + tc*NS);
    #pragma unroll
    for (int q = 0; q < 4; ++q) {
        float4 v = Sp[q];
        h[4*q+0] = v.x; h[4*q+1] = v.y; h[4*q+2] = v.z; h[4*q+3] = v.w;
    }
    float sumdt, rprod;
    int j0 = dir_map(k, l0);
    int dj = (k==0) ? 1 : (k==1) ? -1 : (k==2) ? WW : -WW;
    const float* xcb = xc + (size_t)b*LL*DI;
    float* yb = ybuf + ((size_t)k*BB + b)*LL*DI;   // per-direction output

    if (checkA(A_log, d))
        scan_chunk<true , true>(rows, xcb, yb, j0, dj, dtw, dtb, Dk, A_log, d, h, &sumdt, &rprod);
    else
        scan_chunk<false, true>(rows, xcb, yb, j0, dj, dtw, dtb, Dk, A_log, d, h, &sumdt, &rprod);
}

// ---------------- Kernel F: sum 4 dirs, gate with silu(z), out_proj, + residual (16 pix/block)
__global__ __launch_bounds__(DI) void k_out(
    const float* __restrict__ ybuf, const float* __restrict__ siluz,
    const float* __restrict__ Wout, const float* __restrict__ x,
    float* __restrict__ out)
{
    int pix0 = blockIdx.x * 16;
    int t = threadIdx.x;
    __shared__ float prod[16*DI];      // 12 KB
    const size_t stride4 = (size_t)BB*LL*(DI/4);
    for (int i4 = t; i4 < 16*(DI/4); i4 += DI) {
        size_t g4 = (size_t)pix0*(DI/4) + i4;
        float4 a = ((const float4*)ybuf)[g4];
        float4 b1 = ((const float4*)ybuf)[g4 + stride4];
        float4 c1 = ((const float4*)ybuf)[g4 + 2*stride4];
        float4 d1 = ((const float4*)ybuf)[g4 + 3*stride4];
        float4 z = ((const float4*)siluz)[g4];
        float4 r;
        r.x = (a.x+b1.x+c1.x+d1.x) * z.x;
        r.y = (a.y+b1.y+c1.y+d1.y) * z.y;
        r.z = (a.z+b1.z+c1.z+d1.z) * z.z;
        r.w = (a.w+b1.w+c1.w+d1.w) * z.w;
        ((float4*)prod)[i4] = r;
    }
    __syncthreads();
    int ph = t / CM;                   // 0 or 1 -> pixels ph*8 .. ph*8+7
    int oc = t - ph*CM;
    {
        float acc[8];
        #pragma unroll
        for (int p = 0; p < 8; ++p) acc[p] = x[(size_t)(pix0+ph*8+p)*CM + oc];
        const float4* pv = (const float4*)prod;
        for (int c4 = 0; c4 < DI/4; ++c4) {
            float w0 = Wout[(size_t)(4*c4+0)*CM + oc];
            float w1 = Wout[(size_t)(4*c4+1)*CM + oc];
            float w2 = Wout[(size_t)(4*c4+2)*CM + oc];
            float w3 = Wout[(size_t)(4*c4+3)*CM + oc];
            #pragma unroll
            for (int p = 0; p < 8; ++p) {
                float4 xv = pv[(ph*8+p)*48 + c4];
                acc[p] = fmaf(xv.x, w0, acc[p]);
                acc[p] = fmaf(xv.y, w1, acc[p]);
                acc[p] = fmaf(xv.z, w2, acc[p]);
                acc[p] = fmaf(xv.w, w3, acc[p]);
            }
        }
        #pragma unroll
        for (int p = 0; p < 8; ++p) out[(size_t)(pix0+ph*8+p)*CM + oc] = acc[p];
    }
}

extern "C" void kernel_launch(void* const* d_in, const int* in_sizes, int n_in,
                              void* d_out, int out_size, void* d_ws, size_t ws_size,
                              hipStream_t stream) {
    const float* x        = (const float*)d_in[0];
    const float* ln_g     = (const float*)d_in[1];
    const float* ln_b     = (const float*)d_in[2];
    const float* in_projw = (const float*)d_in[3];
    const float* conv_w   = (const float*)d_in[4];
    const float* conv_b   = (const float*)d_in[5];
    const float* x_projw  = (const float*)d_in[6];
    const float* dt_w     = (const float*)d_in[7];
    const float* dt_b     = (const float*)d_in[8];
    const float* A_log    = (const float*)d_in[9];
    const float* Ds       = (const float*)d_in[10];
    const float* out_projw= (const float*)d_in[11];
    float* out = (float*)d_out;

    // workspace layout (floats) — ~90 MB (ws is 256 MB)
    float* ws = (float*)d_ws;
    size_t n192 = (size_t)NPIX * DI;          // 1,204,224
    size_t n132 = (size_t)NPIX * SSMW4;       // 827,904
    size_t nchk = (size_t)4*BB*NC*DI;         // 301,056
    float* xproj = ws;
    float* siluz = xproj + n192;
    float* xc    = siluz + n192;
    float* ssm   = xc + n192;
    float* ybuf  = ssm + n132;                // 4 * n192
    float* Hbuf  = ybuf + 4*n192;             // nchk * NS
    float* Sbuf  = Hbuf + nchk*NS;            // nchk * NS
    float* sdbuf = xproj;                     // alias: xproj dead after k_convx
    float* rpbuf = xproj + nchk;              // alias: fits (nchk*2 < n192)

    k_ln_inproj<<<NPIX/16, 384, 0, stream>>>(x, ln_g, ln_b, in_projw, xproj, siluz);
    k_convx<<<BB*HH*(WW/8), DI, 0, stream>>>(xproj, conv_w, conv_b, x_projw, xc, ssm);
    k_scan1<<<4*BB*NC, DI, 0, stream>>>(ssm, xc, A_log, dt_w, dt_b, Hbuf, sdbuf, rpbuf);
    k_scan2<<<4*BB*DI, 256, 0, stream>>>(Hbuf, Sbuf, sdbuf, rpbuf, A_log);
    k_scan3<<<4*BB*NC, DI, 0, stream>>>(ssm, xc, A_log, dt_w, dt_b, Ds, Sbuf, ybuf);
    k_out<<<NPIX/16, DI, 0, stream>>>(ybuf, siluz, out_projw, x, out);
}

// Round 14
// 182.841 us; speedup vs baseline: 4.4625x; 1.0931x over previous
//
#include <hip/hip_runtime.h>
#include <hip/hip_bf16.h>
#include <math.h>

// Problem constants (from reference)
#define BB 2
#define HH 56
#define WW 56
#define LL (HH*WW)          // 3136
#define CM 96               // D_MODEL
#define DI 192              // D_INNER
#define NS 16               // D_STATE
#define NPIX (BB*LL)        // 6272
#define PROJ2 (2*DI)        // 384
#define SSMW (2*NS+1)       // 33
#define SSMW4 (4*SSMW)      // 132

// chunked scan decomposition: 3136 = NC * LC
#define NC 196
#define LC 16
#define RPAD 36             // padded LDS row: B[16] @0, C[16] @16, dt_raw @32 (144B, 16B-aligned)
#define GPB 16              // scan2: groups per block
#define CPG 13              // scan2: chunks per group (15*13 + 1 = 196)

__device__ __forceinline__ float sigmoidf_(float v) { return 1.f / (1.f + __expf(-v)); }

__device__ __forceinline__ int dir_map(int k, int l) {
    if (k == 0) return l;
    if (k == 1) return LL - 1 - l;
    int l2 = (k == 2) ? l : (LL - 1 - l);
    return (l2 % HH) * WW + (l2 / HH);   // column-major <-> row-major remap
}

// ---------------- Kernel A: LayerNorm + in_proj (96 -> 384), 8 px/block, 2 cols/thread
__global__ __launch_bounds__(DI) void k_ln_inproj(
    const float* __restrict__ x, const float* __restrict__ g, const float* __restrict__ bta,
    const float* __restrict__ W, float* __restrict__ xproj, float* __restrict__ siluz)
{
    int pix0 = blockIdx.x * 8;
    int t = threadIdx.x;
    __shared__ float xs[8*96];         // 3 KB
    ((float4*)xs)[t] = ((const float4*)(x + (size_t)pix0*CM))[t];   // 192 float4 = 768 floats
    __syncthreads();
    if (t < 128) {
        int p = t >> 4, ln = t & 15;     // 8 pixels x 16 lanes
        float v[6]; float s = 0.f;
        #pragma unroll
        for (int i = 0; i < 6; ++i) { v[i] = xs[p*96 + ln + 16*i]; s += v[i]; }
        #pragma unroll
        for (int o = 8; o; o >>= 1) s += __shfl_xor(s, o, 16);
        float mu = s * (1.f/96.f);
        float q = 0.f;
        #pragma unroll
        for (int i = 0; i < 6; ++i) { float dvi = v[i]-mu; q += dvi*dvi; }
        #pragma unroll
        for (int o = 8; o; o >>= 1) q += __shfl_xor(q, o, 16);
        float rstd = rsqrtf(q*(1.f/96.f) + 1e-5f);
        #pragma unroll
        for (int i = 0; i < 6; ++i)
            xs[p*96 + ln + 16*i] = (v[i]-mu)*rstd*g[ln+16*i] + bta[ln+16*i];
    }
    __syncthreads();
    float a0[8], a1[8];
    #pragma unroll
    for (int p = 0; p < 8; ++p) { a0[p] = 0.f; a1[p] = 0.f; }
    const float4* xsv = (const float4*)xs;
    for (int c4 = 0; c4 < CM/4; ++c4) {
        float w00 = W[(size_t)(4*c4+0)*PROJ2 + t],    w01 = W[(size_t)(4*c4+1)*PROJ2 + t];
        float w02 = W[(size_t)(4*c4+2)*PROJ2 + t],    w03 = W[(size_t)(4*c4+3)*PROJ2 + t];
        float w10 = W[(size_t)(4*c4+0)*PROJ2 + t+DI], w11 = W[(size_t)(4*c4+1)*PROJ2 + t+DI];
        float w12 = W[(size_t)(4*c4+2)*PROJ2 + t+DI], w13 = W[(size_t)(4*c4+3)*PROJ2 + t+DI];
        #pragma unroll
        for (int p = 0; p < 8; ++p) {
            float4 xv = xsv[p*24 + c4];
            a0[p] = fmaf(xv.x, w00, a0[p]); a0[p] = fmaf(xv.y, w01, a0[p]);
            a0[p] = fmaf(xv.z, w02, a0[p]); a0[p] = fmaf(xv.w, w03, a0[p]);
            a1[p] = fmaf(xv.x, w10, a1[p]); a1[p] = fmaf(xv.y, w11, a1[p]);
            a1[p] = fmaf(xv.z, w12, a1[p]); a1[p] = fmaf(xv.w, w13, a1[p]);
        }
    }
    #pragma unroll
    for (int p = 0; p < 8; ++p) {
        xproj[(size_t)(pix0+p)*DI + t] = a0[p];           // cols 0..191
        float v = a1[p];                                   // cols 192..383 -> z
        siluz[(size_t)(pix0+p)*DI + t] = v * sigmoidf_(v);
    }
}

// ---------------- Kernel B: depthwise 3x3 conv + SiLU fused with ssm projection
__global__ __launch_bounds__(DI) void k_convx(
    const float* __restrict__ xproj, const float* __restrict__ cw, const float* __restrict__ cb,
    const float* __restrict__ W2, float* __restrict__ xc, float* __restrict__ ssm)
{
    int blk = blockIdx.x;                  // b*HH*7 + h*7 + wq
    int wq = blk % 7; int rest = blk / 7;
    int h = rest % HH; int b = rest / HH;
    int w0 = wq * 8;
    int t = threadIdx.x;                   // channel
    __shared__ float xs[3][10][DI];        // 23 KB halo tile
    __shared__ float xcs[8*DI];            // 6 KB conv outputs
    for (int i4 = t; i4 < 3*10*(DI/4); i4 += DI) {
        int c4 = i4 % (DI/4); int col = (i4/(DI/4)) % 10; int row = i4 / (10*(DI/4));
        int hh = h - 1 + row, ww = w0 - 1 + col;
        float4 v = {0.f,0.f,0.f,0.f};
        if (hh >= 0 && hh < HH && ww >= 0 && ww < WW)
            v = ((const float4*)(xproj + ((size_t)(b*LL + hh*WW + ww))*DI))[c4];
        ((float4*)&xs[row][col][0])[c4] = v;
    }
    __syncthreads();
    float wgt[9];
    #pragma unroll
    for (int q = 0; q < 9; ++q) wgt[q] = cw[t*9 + q];
    float bias = cb[t];
    int pixbase = b*LL + h*WW + w0;
    #pragma unroll
    for (int dw = 0; dw < 8; ++dw) {
        float acc = bias;
        #pragma unroll
        for (int r = 0; r < 3; ++r)
            #pragma unroll
            for (int cc = 0; cc < 3; ++cc)
                acc = fmaf(xs[r][dw+cc][t], wgt[r*3+cc], acc);
        float v = acc * sigmoidf_(acc);
        xc[((size_t)(pixbase + dw))*DI + t] = v;
        xcs[dw*DI + t] = v;
    }
    __syncthreads();
    if (t < SSMW4) {
        float acc[8] = {0.f,0.f,0.f,0.f,0.f,0.f,0.f,0.f};
        const float4* xsv = (const float4*)xcs;
        for (int c4 = 0; c4 < DI/4; ++c4) {
            float w0_ = W2[(size_t)(4*c4+0)*SSMW4 + t];
            float w1_ = W2[(size_t)(4*c4+1)*SSMW4 + t];
            float w2_ = W2[(size_t)(4*c4+2)*SSMW4 + t];
            float w3_ = W2[(size_t)(4*c4+3)*SSMW4 + t];
            #pragma unroll
            for (int p = 0; p < 8; ++p) {
                float4 xv = xsv[p*48 + c4];
                acc[p] = fmaf(xv.x, w0_, acc[p]);
                acc[p] = fmaf(xv.y, w1_, acc[p]);
                acc[p] = fmaf(xv.z, w2_, acc[p]);
                acc[p] = fmaf(xv.w, w3_, acc[p]);
            }
        }
        #pragma unroll
        for (int p = 0; p < 8; ++p) ssm[(size_t)(pixbase+p)*SSMW4 + t] = acc[p];
    }
}

// stage LC rows of the 33-wide ssm slice into padded LDS layout:
// lds[r*RPAD + 0..15] = B, [16..31] = C, [32] = dt_raw
__device__ __forceinline__ void stage_rows(float* rows, const float* ssmb, int l0, int d) {
    for (int i = d; i < LC*SSMW; i += DI) {
        int r = i / SSMW, w = i % SSMW;
        int dst = (w == 0) ? 32 : (w - 1);
        rows[r*RPAD + dst] = ssmb[(size_t)(l0 + r)*SSMW4 + w];
    }
}

// per-chunk scan body.  FAST: exploits A[d][n] = n+1 (verified at runtime) so
// dA_n = r^(n+1) with r = sigmoid(-pre) — no per-n transcendentals.
template<bool FAST, bool WRITEY>
__device__ __forceinline__ void scan_chunk(
    const float* rows, const float* xcb, float* yb,
    int j0, int dj, float dtw, float dtb, float Dk,
    const float* A_log, int d, float* h, float* sumdt_out, float* rprod_out)
{
    float negA[NS];
    if (!FAST) {
        #pragma unroll
        for (int n = 0; n < NS; ++n) negA[n] = -__expf(A_log[d*NS + n]);
    }
    float sumdt = 0.f;
    float rprod = 1.f;
    int j = j0;
    for (int li = 0; li < LC; ++li) {
        const float4* Bv = (const float4*)(rows + li*RPAD);
        const float4* Cv = Bv + 4;
        float pre = fmaf(rows[li*RPAD + 32], dtw, dtb);
        float t1 = __expf(-fabsf(pre));
        float opt = 1.f + t1;
        float dt = fmaxf(pre, 0.f) + __logf(opt);     // softplus, stable
        sumdt += dt;
        float xt = xcb[(size_t)j*DI + d];
        float dx = dt * xt;
        float pw[NS];
        if (FAST) {
            // r = exp(-dt) = sigmoid(-pre);  pw[n] = r^(n+1), depth-4 mul tree
            float r = ((pre >= 0.f) ? t1 : 1.f) * __builtin_amdgcn_rcpf(opt);
            rprod *= r;
            pw[0]=r;          pw[1]=r*r;        pw[2]=pw[1]*r;     pw[3]=pw[1]*pw[1];
            pw[4]=pw[3]*r;    pw[5]=pw[3]*pw[1];pw[6]=pw[3]*pw[2]; pw[7]=pw[3]*pw[3];
            pw[8]=pw[7]*r;    pw[9]=pw[7]*pw[1];pw[10]=pw[7]*pw[2];pw[11]=pw[7]*pw[3];
            pw[12]=pw[7]*pw[4];pw[13]=pw[7]*pw[5];pw[14]=pw[7]*pw[6];pw[15]=pw[7]*pw[7];
        } else {
            #pragma unroll
            for (int n = 0; n < NS; ++n) pw[n] = __expf(dt * negA[n]);
        }
        float y0 = 0.f, y1 = 0.f;
        #pragma unroll
        for (int q = 0; q < 4; ++q) {
            float4 bq = Bv[q];
            h[4*q+0] = fmaf(pw[4*q+0], h[4*q+0], dx * bq.x);
            h[4*q+1] = fmaf(pw[4*q+1], h[4*q+1], dx * bq.y);
            h[4*q+2] = fmaf(pw[4*q+2], h[4*q+2], dx * bq.z);
            h[4*q+3] = fmaf(pw[4*q+3], h[4*q+3], dx * bq.w);
            if (WRITEY) {
                float4 cq = Cv[q];
                y0 = fmaf(h[4*q+0], cq.x, y0);
                y1 = fmaf(h[4*q+1], cq.y, y1);
                y0 = fmaf(h[4*q+2], cq.z, y0);
                y1 = fmaf(h[4*q+3], cq.w, y1);
            }
        }
        if (WRITEY) yb[(size_t)j*DI + d] = fmaf(xt, Dk, y0 + y1);
        // incremental direction map: +1 / -1 / +56 wrap / -56 wrap
        j += dj;
        if (j >= LL) j -= LL-1; else if (j < 0) j += LL-1;
    }
    *sumdt_out = sumdt;
    *rprod_out = rprod;
}

__device__ __forceinline__ bool checkA(const float* A_log, int d) {
    bool ok = true;
    #pragma unroll
    for (int n = 0; n < NS; ++n) {
        float a = __expf(A_log[d*NS + n]);
        ok = ok && (fabsf(a - (float)(n+1)) < 1e-3f);
    }
    return ok;
}

// ---------------- Scan phase 1: per-chunk local scan (h_in = 0)
// Outputs in scan-major layout: Hbuf[((kb*DI+d)*NC + c)*NS + n], sdbuf/rpbuf[(kb*DI+d)*NC + c]
__global__ __launch_bounds__(DI) void k_scan1(
    const float* __restrict__ ssm, const float* __restrict__ xc,
    const float* __restrict__ A_log, const float* __restrict__ dt_w,
    const float* __restrict__ dt_b,
    float* __restrict__ Hbuf, float* __restrict__ sdbuf, float* __restrict__ rpbuf)
{
    int idx = blockIdx.x;          // ((k*2+b)*NC + c)
    int c  = idx % NC;
    int kb = idx / NC;
    int b = kb & 1;
    int k = kb >> 1;
    int d = threadIdx.x;

    __shared__ float rows[LC*RPAD];
    const float* ssmb = ssm + (size_t)b*LL*SSMW4 + SSMW*k;
    int l0 = c * LC;
    stage_rows(rows, ssmb, l0, d);
    __syncthreads();

    float dtw = dt_w[k*DI + d];
    float dtb = dt_b[k*DI + d];
    float h[NS];
    #pragma unroll
    for (int n = 0; n < NS; ++n) h[n] = 0.f;
    float sumdt, rprod;
    int j0 = dir_map(k, l0);
    int dj = (k==0) ? 1 : (k==1) ? -1 : (k==2) ? WW : -WW;
    const float* xcb = xc + (size_t)b*LL*DI;

    if (checkA(A_log, d))
        scan_chunk<true , false>(rows, xcb, nullptr, j0, dj, dtw, dtb, 0.f, A_log, d, h, &sumdt, &rprod);
    else
        scan_chunk<false, false>(rows, xcb, nullptr, j0, dj, dtw, dtb, 0.f, A_log, d, h, &sumdt, &rprod);

    size_t tc = (size_t)kb*DI*NC + (size_t)d*NC + c;      // transposed chunk index
    float4* Hp = (float4*)(Hbuf + tc*NS);
    #pragma unroll
    for (int q = 0; q < 4; ++q) Hp[q] = make_float4(h[4*q+0], h[4*q+1], h[4*q+2], h[4*q+3]);
    sdbuf[tc] = sumdt;
    rpbuf[tc] = rprod;
}

// ---------------- Scan phase 2: block-parallel exclusive prefix per (kb,d).
__global__ __launch_bounds__(256) void k_scan2(
    const float* __restrict__ Hbuf, float* __restrict__ Sbuf,
    const float* __restrict__ sdbuf, const float* __restrict__ rpbuf,
    const float* __restrict__ A_log)
{
    int wid = blockIdx.x;            // kb*DI + d
    int d  = wid % DI;
    int t = threadIdx.x;
    int n = t & 15, g = t >> 4;
    bool fast = checkA(A_log, d);
    float negA = -__expf(A_log[d*NS + n]);
    int e = n + 1;
    size_t base = (size_t)wid * NC;
    int c0 = g * CPG;

    __shared__ float Ag[GPB][16], Hg[GPB][16], Sg[GPB][16];

    float Pv[CPG], Hl[CPG];
    float A = 1.f, H = 0.f;
    #pragma unroll
    for (int i = 0; i < CPG; ++i) {
        bool ok = (c0 + i) < NC;
        size_t c = base + (ok ? c0 + i : 0);
        float P;
        if (fast) {
            float r = rpbuf[c];
            float p2=r*r, p4=p2*p2, p8=p4*p4;
            P = ((e&1)?r:1.f)*((e&2)?p2:1.f)*((e&4)?p4:1.f)*((e&8)?p8:1.f)*((e&16)?p8*p8:1.f);
        } else {
            P = __expf(negA * sdbuf[c]);
        }
        float hl = Hbuf[c*NS + n];
        if (!ok) { P = 1.f; hl = 0.f; }   // identity map for tail lanes
        Pv[i] = P; Hl[i] = hl;
        H = fmaf(P, H, hl);
        A *= P;
    }
    Ag[g][n] = A; Hg[g][n] = H;
    __syncthreads();
    if (t < 16) {
        float s = 0.f;
        #pragma unroll
        for (int gg = 0; gg < GPB; ++gg) {
            Sg[gg][t] = s;
            s = fmaf(Ag[gg][t], s, Hg[gg][t]);
        }
    }
    __syncthreads();
    float s = Sg[g][n];
    #pragma unroll
    for (int i = 0; i < CPG; ++i) {
        if ((c0 + i) < NC) Sbuf[(base + c0 + i)*NS + n] = s;
        s = fmaf(Pv[i], s, Hl[i]);
    }
}

// ---------------- Scan phase 3: re-scan chunk from incoming state, write y per direction
__global__ __launch_bounds__(DI) void k_scan3(
    const float* __restrict__ ssm, const float* __restrict__ xc,
    const float* __restrict__ A_log, const float* __restrict__ dt_w,
    const float* __restrict__ dt_b, const float* __restrict__ Ds,
    const float* __restrict__ Sbuf, float* __restrict__ ybuf)
{
    int idx = blockIdx.x;
    int c  = idx % NC;
    int kb = idx / NC;
    int b = kb & 1;
    int k = kb >> 1;
    int d = threadIdx.x;

    __shared__ float rows[LC*RPAD];
    const float* ssmb = ssm + (size_t)b*LL*SSMW4 + SSMW*k;
    int l0 = c * LC;
    stage_rows(rows, ssmb, l0, d);
    __syncthreads();

    float dtw = dt_w[k*DI + d];
    float dtb = dt_b[k*DI + d];
    float Dk  = Ds[k*DI + d];
    float h[NS];
    size_t tc = (size_t)kb*DI*NC + (size_t)d*NC + c;      // transposed chunk index
    const float4* Sp = (const float4*)(Sbuf + tc*NS);
    #pragma unroll
    for (int q = 0; q < 4; ++q) {
        float4 v = Sp[q];
        h[4*q+0] = v.x; h[4*q+1] = v.y; h[4*q+2] = v.z; h[4*q+3] = v.w;
    }
    float sumdt, rprod;
    int j0 = dir_map(k, l0);
    int dj = (k==0) ? 1 : (k==1) ? -1 : (k==2) ? WW : -WW;
    const float* xcb = xc + (size_t)b*LL*DI;
    float* yb = ybuf + ((size_t)k*BB + b)*LL*DI;   // per-direction output

    if (checkA(A_log, d))
        scan_chunk<true , true>(rows, xcb, yb, j0, dj, dtw, dtb, Dk, A_log, d, h, &sumdt, &rprod);
    else
        scan_chunk<false, true>(rows, xcb, yb, j0, dj, dtw, dtb, Dk, A_log, d, h, &sumdt, &rprod);
}

// ---------------- Kernel F: sum 4 dirs, gate with silu(z), out_proj, + residual (8 px/block)
__global__ __launch_bounds__(DI) void k_out(
    const float* __restrict__ ybuf, const float* __restrict__ siluz,
    const float* __restrict__ Wout, const float* __restrict__ x,
    float* __restrict__ out)
{
    int pix0 = blockIdx.x * 8;
    int t = threadIdx.x;
    __shared__ float prod[8*DI];       // 6 KB
    const size_t stride4 = (size_t)BB*LL*(DI/4);
    for (int i4 = t; i4 < 8*(DI/4); i4 += DI) {
        size_t g4 = (size_t)pix0*(DI/4) + i4;
        float4 a = ((const float4*)ybuf)[g4];
        float4 b1 = ((const float4*)ybuf)[g4 + stride4];
        float4 c1 = ((const float4*)ybuf)[g4 + 2*stride4];
        float4 d1 = ((const float4*)ybuf)[g4 + 3*stride4];
        float4 z = ((const float4*)siluz)[g4];
        float4 r;
        r.x = (a.x+b1.x+c1.x+d1.x) * z.x;
        r.y = (a.y+b1.y+c1.y+d1.y) * z.y;
        r.z = (a.z+b1.z+c1.z+d1.z) * z.z;
        r.w = (a.w+b1.w+c1.w+d1.w) * z.w;
        ((float4*)prod)[i4] = r;
    }
    __syncthreads();
    int half = t / CM;                 // 0 or 1 -> pixels half*4 .. half*4+3
    int oc = t - half*CM;
    float acc[4];
    #pragma unroll
    for (int p = 0; p < 4; ++p) acc[p] = x[(size_t)(pix0 + half*4 + p)*CM + oc];
    const float4* pv = (const float4*)prod;
    for (int c4 = 0; c4 < DI/4; ++c4) {
        float w0 = Wout[(size_t)(4*c4+0)*CM + oc];
        float w1 = Wout[(size_t)(4*c4+1)*CM + oc];
        float w2 = Wout[(size_t)(4*c4+2)*CM + oc];
        float w3 = Wout[(size_t)(4*c4+3)*CM + oc];
        #pragma unroll
        for (int p = 0; p < 4; ++p) {
            float4 xv = pv[(half*4 + p)*48 + c4];
            acc[p] = fmaf(xv.x, w0, acc[p]);
            acc[p] = fmaf(xv.y, w1, acc[p]);
            acc[p] = fmaf(xv.z, w2, acc[p]);
            acc[p] = fmaf(xv.w, w3, acc[p]);
        }
    }
    #pragma unroll
    for (int p = 0; p < 4; ++p) out[(size_t)(pix0 + half*4 + p)*CM + oc] = acc[p];
}

extern "C" void kernel_launch(void* const* d_in, const int* in_sizes, int n_in,
                              void* d_out, int out_size, void* d_ws, size_t ws_size,
                              hipStream_t stream) {
    const float* x        = (const float*)d_in[0];
    const float* ln_g     = (const float*)d_in[1];
    const float* ln_b     = (const float*)d_in[2];
    const float* in_projw = (const float*)d_in[3];
    const float* conv_w   = (const float*)d_in[4];
    const float* conv_b   = (const float*)d_in[5];
    const float* x_projw  = (const float*)d_in[6];
    const float* dt_w     = (const float*)d_in[7];
    const float* dt_b     = (const float*)d_in[8];
    const float* A_log    = (const float*)d_in[9];
    const float* Ds       = (const float*)d_in[10];
    const float* out_projw= (const float*)d_in[11];
    float* out = (float*)d_out;

    // workspace layout (floats) — ~90 MB (ws is 256 MB)
    float* ws = (float*)d_ws;
    size_t n192 = (size_t)NPIX * DI;          // 1,204,224
    size_t n132 = (size_t)NPIX * SSMW4;       // 827,904
    size_t nchk = (size_t)4*BB*NC*DI;         // 301,056
    float* xproj = ws;
    float* siluz = xproj + n192;
    float* xc    = siluz + n192;
    float* ssm   = xc + n192;
    float* ybuf  = ssm + n132;                // 4 * n192
    float* Hbuf  = ybuf + 4*n192;             // nchk * NS
    float* Sbuf  = Hbuf + nchk*NS;            // nchk * NS
    float* sdbuf = xproj;                     // alias: xproj dead after k_convx
    float* rpbuf = xproj + nchk;              // alias: fits (nchk*2 < n192)

    k_ln_inproj<<<NPIX/8, DI, 0, stream>>>(x, ln_g, ln_b, in_projw, xproj, siluz);
    k_convx<<<BB*HH*(WW/8), DI, 0, stream>>>(xproj, conv_w, conv_b, x_projw, xc, ssm);
    k_scan1<<<4*BB*NC, DI, 0, stream>>>(ssm, xc, A_log, dt_w, dt_b, Hbuf, sdbuf, rpbuf);
    k_scan2<<<4*BB*DI, 256, 0, stream>>>(Hbuf, Sbuf, sdbuf, rpbuf, A_log);
    k_scan3<<<4*BB*NC, DI, 0, stream>>>(ssm, xc, A_log, dt_w, dt_b, Ds, Sbuf, ybuf);
    k_out<<<NPIX/8, DI, 0, stream>>>(ybuf, siluz, out_projw, x, out);
}